// Round 1
// baseline (188.496 us; speedup 1.0000x reference)
//
#include <hip/hip_runtime.h>
#include <hip/hip_bf16.h>

#define QUERY_DIM 128
#define HIDDEN 128

// ---------------------------------------------------------------------------
// Kernel 1: W[e][d] = sum_h WQ[h][e] * WK[h][d]   (128x128 = 64KB, trivial)
// ---------------------------------------------------------------------------
__global__ void wqk_kernel(const float* __restrict__ WQ,
                           const float* __restrict__ WK,
                           float* __restrict__ W) {
    int e = blockIdx.x;    // 0..127
    int d = threadIdx.x;   // 0..127
    float acc = 0.f;
#pragma unroll 8
    for (int h = 0; h < HIDDEN; ++h) {
        acc += WQ[h * QUERY_DIM + e] * WK[h * 128 + d];
    }
    W[e * 128 + d] = acc;
}

// ---------------------------------------------------------------------------
// Kernel 2: R = query @ W     [nmols, 128] -> scratch
// 128 threads/block, 8 rows per block. W staged in LDS in two 32KB halves.
// ---------------------------------------------------------------------------
__global__ void qproj_kernel(const float* __restrict__ Q,
                             const float* __restrict__ W,
                             float* __restrict__ R, int nmols) {
    __shared__ float wl[64 * 128];  // 32 KB (half of W)
    __shared__ float ql[8 * 128];   // 4 KB (8 query rows)
    int t = threadIdx.x;            // 0..127
    int row0 = blockIdx.x * 8;

    // stage 8 query rows (1024 floats) via float4
    for (int i = t * 4; i < 8 * 128; i += 128 * 4) {
        *(float4*)&ql[i] = *(const float4*)&Q[(long)row0 * QUERY_DIM + i];
    }

    float acc[8] = {0.f, 0.f, 0.f, 0.f, 0.f, 0.f, 0.f, 0.f};

    for (int half = 0; half < 2; ++half) {
        __syncthreads();
        for (int i = t * 4; i < 64 * 128; i += 128 * 4) {
            *(float4*)&wl[i] = *(const float4*)&W[half * 64 * 128 + i];
        }
        __syncthreads();
        for (int d = 0; d < 64; ++d) {
            float wv = wl[d * 128 + t];      // consecutive t -> 2-way (free)
            int dg = half * 64 + d;
#pragma unroll
            for (int r = 0; r < 8; ++r) {
                acc[r] += ql[r * 128 + dg] * wv;   // broadcast (free)
            }
        }
    }
#pragma unroll
    for (int r = 0; r < 8; ++r) {
        if (row0 + r < nmols) R[(long)(row0 + r) * 128 + t] = acc[r];
    }
}

// ---------------------------------------------------------------------------
// Kernel 3 (dominant): scores[k] = (key[k] . R[idx[k]]) / sqrt(128)
// Half-wave (32 lanes) per key, float4 per lane = 512B/row fully coalesced.
// ---------------------------------------------------------------------------
__global__ void score_kernel(const float* __restrict__ K,
                             const float* __restrict__ R,
                             const int* __restrict__ idx,
                             float* __restrict__ scores, int total) {
    int t = threadIdx.x;
    int half = t >> 5;          // 0..7 within 256-thread block
    int lane = t & 31;
    long k = (long)blockIdx.x * 8 + half;
    if (k >= total) return;
    int m = idx[k];
    float4 kv = ((const float4*)(K + k * 128))[lane];
    float4 rv = ((const float4*)(R + (long)m * 128))[lane];
    float s = kv.x * rv.x + kv.y * rv.y + kv.z * rv.z + kv.w * rv.w;
    // reduce within the 32-lane group (xor masks <32 stay inside the group)
#pragma unroll
    for (int off = 16; off > 0; off >>= 1) s += __shfl_xor(s, off, 64);
    if (lane == 0) scores[k] = s * 0.08838834764831845f;  // 1/sqrt(128)
}

// ---------------------------------------------------------------------------
// Kernel 4: segment starts via binary search (idx is sorted)
// ---------------------------------------------------------------------------
__global__ void segstart_kernel(const int* __restrict__ idx,
                                int* __restrict__ start, int nmols, int total) {
    int m = blockIdx.x * blockDim.x + threadIdx.x;
    if (m > nmols) return;
    if (m == nmols) { start[m] = total; return; }
    int lo = 0, hi = total;
    while (lo < hi) {
        int mid = (lo + hi) >> 1;
        if (idx[mid] < m) lo = mid + 1; else hi = mid;
    }
    start[m] = lo;
}

// ---------------------------------------------------------------------------
// Kernel 5: segment softmax. One wave (64 lanes) per segment, 3 passes.
// Avg segment length ~64 keys; scores region is 4MB (L2-resident).
// ---------------------------------------------------------------------------
__global__ void softmax_kernel(const float* __restrict__ scores,
                               const int* __restrict__ start,
                               float* __restrict__ weights, int nmols) {
    int wid = blockIdx.x * (blockDim.x >> 6) + (threadIdx.x >> 6);
    int lane = threadIdx.x & 63;
    if (wid >= nmols) return;
    int s0 = start[wid], s1 = start[wid + 1];

    float mx = -__builtin_inff();
    for (int i = s0 + lane; i < s1; i += 64) mx = fmaxf(mx, scores[i]);
#pragma unroll
    for (int off = 32; off > 0; off >>= 1) mx = fmaxf(mx, __shfl_xor(mx, off, 64));

    float sum = 0.f;
    for (int i = s0 + lane; i < s1; i += 64) sum += __expf(scores[i] - mx);
#pragma unroll
    for (int off = 32; off > 0; off >>= 1) sum += __shfl_xor(sum, off, 64);

    float inv = 1.0f / sum;
    for (int i = s0 + lane; i < s1; i += 64)
        weights[i] = __expf(scores[i] - mx) * inv;
}

// ---------------------------------------------------------------------------
extern "C" void kernel_launch(void* const* d_in, const int* in_sizes, int n_in,
                              void* d_out, int out_size, void* d_ws, size_t ws_size,
                              hipStream_t stream) {
    const float* Q   = (const float*)d_in[0];
    const float* K   = (const float*)d_in[1];
    const float* WQ  = (const float*)d_in[2];
    const float* WK  = (const float*)d_in[3];
    const int*   idx = (const int*)d_in[4];

    const int nmols = in_sizes[0] / QUERY_DIM;   // 16384
    const int total = in_sizes[4];               // 1048576

    float* weights = (float*)d_out;              // output 0
    float* scores  = (float*)d_out + total;      // output 1

    char* ws = (char*)d_ws;
    float* W        = (float*)ws;                        // 64 KB
    int*   segstart = (int*)(ws + 65536);                // (nmols+1)*4 ~ 64 KB
    float* R        = (float*)(ws + 65536 + 131072);     // nmols*128*4 = 8 MB

    // W = WQ^T @ WK
    wqk_kernel<<<128, 128, 0, stream>>>(WQ, WK, W);
    // segment boundaries (independent of W)
    segstart_kernel<<<(nmols + 1 + 255) / 256, 256, 0, stream>>>(idx, segstart, nmols, total);
    // R = query @ W
    qproj_kernel<<<(nmols + 7) / 8, 128, 0, stream>>>(Q, W, R, nmols);
    // scores (dominant, memory-bound)
    score_kernel<<<(total + 7) / 8, 256, 0, stream>>>(K, R, idx, scores, total);
    // segment softmax -> weights
    softmax_kernel<<<(nmols + 3) / 4, 256, 0, stream>>>(scores, segstart, weights, nmols);
}

// Round 3
// 142.545 us; speedup vs baseline: 1.3224x; 1.3224x over previous
//
#include <hip/hip_runtime.h>
#include <hip/hip_bf16.h>

#define QUERY_DIM 128
#define HIDDEN 128

typedef float f32x4 __attribute__((ext_vector_type(4)));

// ---------------------------------------------------------------------------
// Kernel 1: W[e][d] = sum_h WQ[h][e] * WK[h][d]   (128x128 = 64KB, trivial)
// ---------------------------------------------------------------------------
__global__ void wqk_kernel(const float* __restrict__ WQ,
                           const float* __restrict__ WK,
                           float* __restrict__ W) {
    int e = blockIdx.x;    // 0..127
    int d = threadIdx.x;   // 0..127
    float acc = 0.f;
#pragma unroll 8
    for (int h = 0; h < HIDDEN; ++h) {
        acc += WQ[h * QUERY_DIM + e] * WK[h * 128 + d];
    }
    W[e * 128 + d] = acc;
}

// ---------------------------------------------------------------------------
// Kernel 2: R = query @ W    [nmols,128]. 16 rows/block, 256 threads.
// thread t: col c = t&127, row-group g = t>>7 (rows g*8 .. g*8+7)
// ---------------------------------------------------------------------------
__global__ __launch_bounds__(256) void qproj_kernel(const float* __restrict__ Q,
                                                    const float* __restrict__ W,
                                                    float* __restrict__ R, int nmols) {
    __shared__ float wl[64 * 128];  // 32 KB (half of W)
    __shared__ float ql[16 * 128];  // 8 KB (16 query rows)
    int t = threadIdx.x;
    int c = t & 127;
    int g = t >> 7;
    long row0 = (long)blockIdx.x * 16;

    for (int i = t * 4; i < 16 * 128; i += 256 * 4) {
        *(float4*)&ql[i] = *(const float4*)&Q[row0 * QUERY_DIM + i];
    }

    float acc[8] = {0.f, 0.f, 0.f, 0.f, 0.f, 0.f, 0.f, 0.f};

    for (int half = 0; half < 2; ++half) {
        __syncthreads();
        for (int i = t * 4; i < 64 * 128; i += 256 * 4) {
            *(float4*)&wl[i] = *(const float4*)&W[half * 64 * 128 + i];
        }
        __syncthreads();
        for (int d = 0; d < 64; ++d) {
            float wv = wl[d * 128 + c];          // consecutive c -> conflict-free
            int dg = half * 64 + d;
#pragma unroll
            for (int r = 0; r < 8; ++r) {
                acc[r] += ql[(g * 8 + r) * 128 + dg] * wv;   // broadcast
            }
        }
    }
#pragma unroll
    for (int r = 0; r < 8; ++r) {
        long row = row0 + g * 8 + r;
        if (row < nmols) R[row * 128 + c] = acc[r];
    }
}

// ---------------------------------------------------------------------------
// Kernel 3 (dominant): scores[k] = (key[k] . R[idx[k]]) / sqrt(128)
// Grid-stride persistent. Half-wave (32 lanes) per 4 keys/iteration:
// 4 idx loads batched first, then 8 dwordx4 loads in flight per lane.
// K loads nontemporal (zero reuse) to keep L2 hot for R.
// ---------------------------------------------------------------------------
__device__ __forceinline__ float dot4(f32x4 a, f32x4 b) {
    return a.x * b.x + a.y * b.y + a.z * b.z + a.w * b.w;
}

__global__ __launch_bounds__(256) void score_kernel(const float* __restrict__ K,
                                                    const float* __restrict__ R,
                                                    const int* __restrict__ idx,
                                                    float* __restrict__ scores, int total) {
    const int t = threadIdx.x;
    const int lane = t & 31;
    const long gh = (((long)blockIdx.x * 256) + t) >> 5;   // global half-wave id
    const long nh = ((long)gridDim.x * 256) >> 5;          // total half-waves
    const float sc = 0.08838834764831845f;                 // 1/sqrt(128)

    for (long k = gh * 4; k < total; k += nh * 4) {
        // batch the independent idx loads first (hide idx->R dependency)
        int m0 = idx[k + 0];
        int m1 = idx[k + 1];
        int m2 = idx[k + 2];
        int m3 = idx[k + 3];
        const f32x4* K0 = (const f32x4*)(K + (k + 0) * 128);
        const f32x4* K1 = (const f32x4*)(K + (k + 1) * 128);
        const f32x4* K2 = (const f32x4*)(K + (k + 2) * 128);
        const f32x4* K3 = (const f32x4*)(K + (k + 3) * 128);
        f32x4 a0 = __builtin_nontemporal_load(&K0[lane]);
        f32x4 a1 = __builtin_nontemporal_load(&K1[lane]);
        f32x4 a2 = __builtin_nontemporal_load(&K2[lane]);
        f32x4 a3 = __builtin_nontemporal_load(&K3[lane]);
        f32x4 r0 = *((const f32x4*)(R + (long)m0 * 128) + lane);
        f32x4 r1 = *((const f32x4*)(R + (long)m1 * 128) + lane);
        f32x4 r2 = *((const f32x4*)(R + (long)m2 * 128) + lane);
        f32x4 r3 = *((const f32x4*)(R + (long)m3 * 128) + lane);
        float s0 = dot4(a0, r0);
        float s1 = dot4(a1, r1);
        float s2 = dot4(a2, r2);
        float s3 = dot4(a3, r3);
#pragma unroll
        for (int off = 16; off > 0; off >>= 1) {
            s0 += __shfl_xor(s0, off, 64);   // xor<32: stays within half-wave
            s1 += __shfl_xor(s1, off, 64);
            s2 += __shfl_xor(s2, off, 64);
            s3 += __shfl_xor(s3, off, 64);
        }
        if (lane == 0) {
            scores[k + 0] = s0 * sc;
            scores[k + 1] = s1 * sc;
            scores[k + 2] = s2 * sc;
            scores[k + 3] = s3 * sc;
        }
    }
}

// ---------------------------------------------------------------------------
// Kernel 4: segment starts via binary search (idx is sorted)
// ---------------------------------------------------------------------------
__global__ void segstart_kernel(const int* __restrict__ idx,
                                int* __restrict__ start, int nmols, int total) {
    int m = blockIdx.x * blockDim.x + threadIdx.x;
    if (m > nmols) return;
    if (m == nmols) { start[m] = total; return; }
    int lo = 0, hi = total;
    while (lo < hi) {
        int mid = (lo + hi) >> 1;
        if (idx[mid] < m) lo = mid + 1; else hi = mid;
    }
    start[m] = lo;
}

// ---------------------------------------------------------------------------
// Kernel 5: segment softmax. One wave per segment, 2 passes over scores:
// pass1 max, pass2 exp (stashed in weights) + sum, pass3 scale weights.
// ---------------------------------------------------------------------------
__global__ void softmax_kernel(const float* __restrict__ scores,
                               const int* __restrict__ start,
                               float* __restrict__ weights, int nmols) {
    int wid = blockIdx.x * (blockDim.x >> 6) + (threadIdx.x >> 6);
    int lane = threadIdx.x & 63;
    if (wid >= nmols) return;
    int s0 = start[wid], s1 = start[wid + 1];

    float mx = -__builtin_inff();
    for (int i = s0 + lane; i < s1; i += 64) mx = fmaxf(mx, scores[i]);
#pragma unroll
    for (int off = 32; off > 0; off >>= 1) mx = fmaxf(mx, __shfl_xor(mx, off, 64));

    float sum = 0.f;
    for (int i = s0 + lane; i < s1; i += 64) {
        float e = __expf(scores[i] - mx);
        weights[i] = e;
        sum += e;
    }
#pragma unroll
    for (int off = 32; off > 0; off >>= 1) sum += __shfl_xor(sum, off, 64);

    float inv = 1.0f / sum;
    for (int i = s0 + lane; i < s1; i += 64) weights[i] *= inv;
}

// ---------------------------------------------------------------------------
extern "C" void kernel_launch(void* const* d_in, const int* in_sizes, int n_in,
                              void* d_out, int out_size, void* d_ws, size_t ws_size,
                              hipStream_t stream) {
    const float* Q   = (const float*)d_in[0];
    const float* K   = (const float*)d_in[1];
    const float* WQ  = (const float*)d_in[2];
    const float* WK  = (const float*)d_in[3];
    const int*   idx = (const int*)d_in[4];

    const int nmols = in_sizes[0] / QUERY_DIM;   // 16384
    const int total = in_sizes[4];               // 1048576

    float* weights = (float*)d_out;              // output 0
    float* scores  = (float*)d_out + total;      // output 1

    char* ws = (char*)d_ws;
    float* W        = (float*)ws;                        // 64 KB
    int*   segstart = (int*)(ws + 65536);                // (nmols+1)*4
    float* R        = (float*)(ws + 65536 + 131072);     // nmols*128*4 = 8 MB

    wqk_kernel<<<128, 128, 0, stream>>>(WQ, WK, W);
    segstart_kernel<<<(nmols + 1 + 255) / 256, 256, 0, stream>>>(idx, segstart, nmols, total);
    qproj_kernel<<<(nmols + 15) / 16, 256, 0, stream>>>(Q, W, R, nmols);
    score_kernel<<<2048, 256, 0, stream>>>(K, R, idx, scores, total);
    softmax_kernel<<<(nmols + 3) / 4, 256, 0, stream>>>(scores, segstart, weights, nmols);
}

// Round 4
// 140.063 us; speedup vs baseline: 1.3458x; 1.0177x over previous
//
#include <hip/hip_runtime.h>
#include <hip/hip_bf16.h>

#define QUERY_DIM 128
#define HIDDEN 128

typedef float f32x4 __attribute__((ext_vector_type(4)));

__device__ __forceinline__ float dot4(f32x4 a, f32x4 b) {
    return a.x * b.x + a.y * b.y + a.z * b.z + a.w * b.w;
}

// ---------------------------------------------------------------------------
// Kernel 1 (combo): blocks 0..63  -> W[e][d] = sum_h WQ[h][e]*WK[h][d]
//                   blocks 64..   -> segment starts via binary search
// ---------------------------------------------------------------------------
__global__ __launch_bounds__(256) void combo_kernel(const float* __restrict__ WQ,
                                                    const float* __restrict__ WK,
                                                    float* __restrict__ W,
                                                    const int* __restrict__ idx,
                                                    int* __restrict__ start,
                                                    int nmols, int total) {
    int b = blockIdx.x;
    int t = threadIdx.x;
    if (b < 64) {
        int e = b * 2 + (t >> 7);   // 0..127
        int d = t & 127;
        float acc = 0.f;
#pragma unroll 8
        for (int h = 0; h < HIDDEN; ++h) {
            acc += WQ[h * QUERY_DIM + e] * WK[h * 128 + d];
        }
        W[e * 128 + d] = acc;
    } else {
        int m = (b - 64) * 256 + t;
        if (m > nmols) return;
        if (m == nmols) { start[m] = total; return; }
        int lo = 0, hi = total;
        while (lo < hi) {
            int mid = (lo + hi) >> 1;
            if (idx[mid] < m) lo = mid + 1; else hi = mid;
        }
        start[m] = lo;
    }
}

// ---------------------------------------------------------------------------
// Kernel 2: R = query @ W    [nmols,128]. 16 rows/block, 256 threads.
// ---------------------------------------------------------------------------
__global__ __launch_bounds__(256) void qproj_kernel(const float* __restrict__ Q,
                                                    const float* __restrict__ W,
                                                    float* __restrict__ R, int nmols) {
    __shared__ float wl[64 * 128];  // 32 KB (half of W)
    __shared__ float ql[16 * 128];  // 8 KB (16 query rows)
    int t = threadIdx.x;
    int c = t & 127;
    int g = t >> 7;
    long row0 = (long)blockIdx.x * 16;

    for (int i = t * 4; i < 16 * 128; i += 256 * 4) {
        *(float4*)&ql[i] = *(const float4*)&Q[row0 * QUERY_DIM + i];
    }

    float acc[8] = {0.f, 0.f, 0.f, 0.f, 0.f, 0.f, 0.f, 0.f};

    for (int half = 0; half < 2; ++half) {
        __syncthreads();
        for (int i = t * 4; i < 64 * 128; i += 256 * 4) {
            *(float4*)&wl[i] = *(const float4*)&W[half * 64 * 128 + i];
        }
        __syncthreads();
        for (int d = 0; d < 64; ++d) {
            float wv = wl[d * 128 + c];
            int dg = half * 64 + d;
#pragma unroll
            for (int r = 0; r < 8; ++r) {
                acc[r] += ql[(g * 8 + r) * 128 + dg] * wv;
            }
        }
    }
#pragma unroll
    for (int r = 0; r < 8; ++r) {
        long row = row0 + g * 8 + r;
        if (row < nmols) R[row * 128 + c] = acc[r];
    }
}

// ---------------------------------------------------------------------------
// Kernel 3 (fused, dominant): per segment — scores + stable softmax.
// One wave per segment (grid-stride over segments). Keys are contiguous
// (idx sorted). R row in registers: one float4/lane per half-wave.
// Phase 1: each half-wave computes one key's dot per iteration (coalesced
//          512B row), butterfly-reduce within half, track running max.
// Phase 2: re-read scores (L1/L2-hot), sum exp.
// Phase 3: weights[i] = exp(scores[i]-mx)*inv  (recompute exp, avoids RMW).
// ---------------------------------------------------------------------------
__global__ __launch_bounds__(256) void fused_kernel(const float* __restrict__ K,
                                                    const float* __restrict__ R,
                                                    const int* __restrict__ start,
                                                    float* __restrict__ weights,
                                                    float* scores,   // no restrict: store+load alias
                                                    int nmols) {
    const int lane = threadIdx.x & 63;
    const int half = lane >> 5;      // 0/1
    const int hl = lane & 31;        // lane within half-wave
    const int wave = (blockIdx.x * 256 + threadIdx.x) >> 6;
    const int nwaves = gridDim.x * 4;
    const float sc = 0.08838834764831845f;  // 1/sqrt(128)

    for (int s = wave; s < nmols; s += nwaves) {
        int s0 = start[s], s1 = start[s + 1];
        if (s0 >= s1) continue;

        // full R row held across each half-wave (32 lanes x float4 = 128)
        f32x4 rfrag = *((const f32x4*)(R + (long)s * 128) + hl);

        // ---- phase 1: scores + running max ----
        float mx = -__builtin_inff();
        for (int k = s0 + half; k < s1; k += 2) {
            f32x4 kv = __builtin_nontemporal_load((const f32x4*)(K + (long)k * 128) + hl);
            float v = dot4(kv, rfrag);
#pragma unroll
            for (int off = 16; off > 0; off >>= 1) v += __shfl_xor(v, off, 64);
            v *= sc;
            if (hl == 0) scores[k] = v;
            mx = fmaxf(mx, v);
        }
        mx = fmaxf(mx, __shfl_xor(mx, 32, 64));   // combine the two halves

        // make the scores stores visible before re-reading (same CU/L1)
        asm volatile("s_waitcnt vmcnt(0)" ::: "memory");

        // ---- phase 2: sum of exp (scores hot in L1/L2) ----
        float sum = 0.f;
        for (int i = s0 + lane; i < s1; i += 64) sum += __expf(scores[i] - mx);
#pragma unroll
        for (int off = 32; off > 0; off >>= 1) sum += __shfl_xor(sum, off, 64);
        float inv = 1.0f / sum;

        // ---- phase 3: weights ----
        for (int i = s0 + lane; i < s1; i += 64)
            weights[i] = __expf(scores[i] - mx) * inv;
    }
}

// ---------------------------------------------------------------------------
extern "C" void kernel_launch(void* const* d_in, const int* in_sizes, int n_in,
                              void* d_out, int out_size, void* d_ws, size_t ws_size,
                              hipStream_t stream) {
    const float* Q   = (const float*)d_in[0];
    const float* K   = (const float*)d_in[1];
    const float* WQ  = (const float*)d_in[2];
    const float* WK  = (const float*)d_in[3];
    const int*   idx = (const int*)d_in[4];

    const int nmols = in_sizes[0] / QUERY_DIM;   // 16384
    const int total = in_sizes[4];               // 1048576

    float* weights = (float*)d_out;              // output 0
    float* scores  = (float*)d_out + total;      // output 1

    char* ws = (char*)d_ws;
    float* W        = (float*)ws;                        // 64 KB
    int*   segstart = (int*)(ws + 65536);                // (nmols+1)*4
    float* R        = (float*)(ws + 65536 + 131072);     // nmols*128*4 = 8 MB

    // W (blocks 0..63) + segment starts (blocks 64..)
    int segblocks = (nmols + 1 + 255) / 256;
    combo_kernel<<<64 + segblocks, 256, 0, stream>>>(WQ, WK, W, idx, segstart, nmols, total);
    // R = query @ W
    qproj_kernel<<<(nmols + 15) / 16, 256, 0, stream>>>(Q, W, R, nmols);
    // fused scores + segment softmax
    fused_kernel<<<2048, 256, 0, stream>>>(K, R, segstart, weights, scores, nmols);
}